// Round 10
// baseline (286.341 us; speedup 1.0000x reference)
//
#include <hip/hip_runtime.h>

// Gate3: out[r][c] = g(x1[r][c>>2]) + g(x2[r][c>>1]) + g(x3[r][c]),
// g(x) = sigmoid(x*w + b) * x; out (B,16,1) == flat (B*16,) fp32.
//
// Memory-bound streaming: 224 MiB read + 128 MiB write, roofline ~59 us
// at 6.3 TB/s. One thread per QUARTER-row (i = row*4 + q): every access
// unit-stride across lanes, 100% utilized:
//   x1: scalar  x1[i]   (4 B/lane)
//   x2: float2  x2[2i]  (8 B/lane)
//   x3: float4  x3[4i]  (16 B/lane)
//   out: float4 out[4i] (16 B/lane)
//
// Measured history:
//  R4 (NT + frcp_rn):   graph 284.4, kernel <79.5 us
//  R5 (no NT + rcp):    graph 300.9, kernel 106 us, 2.4 TB/s, VALU 12%,
//                       Occ 67% -> latency/cache-bound. NT IS LOAD-BEARING.
//  R8 (NT + rcp):       graph 280.8, kernel <79.7 us (~85 us by floor calc)
// R8 change: x2 MLP — unroll grid-stride x2, 6 independent NT loads in
// flight before compute (latency-bound signature: VALU low + Occ low).
// Round-3 note: never pass floats through readfirstlane (int-only builtin).

typedef float v2f __attribute__((ext_vector_type(2)));
typedef float v4f __attribute__((ext_vector_type(4)));

__device__ __forceinline__ float gate(float x, float w, float b) {
    float z = fmaf(x, w, b);
    float s = __builtin_amdgcn_rcpf(1.0f + __expf(-z));   // sigmoid, v_rcp_f32
    return s * x;
}

__device__ __forceinline__ v4f quad_out(float a, v2f b2, v4f c4, float w, float b) {
    float ga  = gate(a, w, b);
    float gb0 = gate(b2.x, w, b);
    float gb1 = gate(b2.y, w, b);
    v4f o;
    o.x = ga + gb0 + gate(c4.x, w, b);
    o.y = ga + gb0 + gate(c4.y, w, b);
    o.z = ga + gb1 + gate(c4.z, w, b);
    o.w = ga + gb1 + gate(c4.w, w, b);
    return o;
}

__global__ __launch_bounds__(256) void gate3_kernel(
    const float* __restrict__ x1,   // (B,4)  flat
    const v2f*  __restrict__ x2,    // (B,8)  flat, as float2
    const v4f*  __restrict__ x3,    // (B,16) flat, as float4
    const float* __restrict__ Wp,
    const float* __restrict__ bp,
    v4f* __restrict__ out,          // (B,16) flat, as float4
    int nquads)                     // B*4
{
    const float w = Wp[0];
    const float b = bp[0];

    const int stride = gridDim.x * blockDim.x;
    for (int i = blockIdx.x * blockDim.x + threadIdx.x; i < nquads; i += 2 * stride) {
        const int j = i + stride;
        const bool hasj = (j < nquads);

        // issue all independent NT loads first (2x MLP)
        float a0 = __builtin_nontemporal_load(&x1[i]);
        v2f  b20 = __builtin_nontemporal_load(&x2[i]);
        v4f  c40 = __builtin_nontemporal_load(&x3[i]);
        float a1 = 0.f; v2f b21 = {0.f, 0.f}; v4f c41 = {0.f, 0.f, 0.f, 0.f};
        if (hasj) {
            a1  = __builtin_nontemporal_load(&x1[j]);
            b21 = __builtin_nontemporal_load(&x2[j]);
            c41 = __builtin_nontemporal_load(&x3[j]);
        }

        v4f o0 = quad_out(a0, b20, c40, w, b);
        __builtin_nontemporal_store(o0, &out[i]);
        if (hasj) {
            v4f o1 = quad_out(a1, b21, c41, w, b);
            __builtin_nontemporal_store(o1, &out[j]);
        }
    }
}

extern "C" void kernel_launch(void* const* d_in, const int* in_sizes, int n_in,
                              void* d_out, int out_size, void* d_ws, size_t ws_size,
                              hipStream_t stream) {
    const float* x1 = (const float*)d_in[0];
    const v2f*   x2 = (const v2f*)d_in[1];
    const v4f*   x3 = (const v4f*)d_in[2];
    const float* W  = (const float*)d_in[3];
    const float* b  = (const float*)d_in[4];
    v4f* out = (v4f*)d_out;

    int nquads = in_sizes[0];             // B*4 = 8388608
    int block  = 256;
    int grid   = 2048;                    // 256 CUs x 8 blocks; 8 unrolled pairs

    gate3_kernel<<<grid, block, 0, stream>>>(x1, x2, x3, W, b, out, nquads);
}